// Round 11
// baseline (49.189 us; speedup 1.0000x reference)
//
#include <hip/hip_runtime.h>

typedef __bf16 bf16;
typedef __bf16 bf16x4 __attribute__((ext_vector_type(4)));
typedef __bf16 bf16x8 __attribute__((ext_vector_type(8)));
typedef float  f32x4  __attribute__((ext_vector_type(4)));

#define ALPHA 0.2f
#define MLP_ALPHA 0.01f
#define LN_EPS 1e-5f

constexpr int Bb = 4;
constexpr int Nn = 4096;
constexpr int Ff = 256;   // FIN == FOUT
constexpr int Kk = 64;    // chunk rows
constexpr int Cc = 64;    // N / k

// d_ws layout (bytes)
constexpr size_t WS_WA   = 524288;    // 1 KB f32[256]      (wfrag = [0, 512K))
constexpr size_t WS_EVEC = 525312;    // 64 KB f32[16384]   (leaky'd e per global row)
constexpr size_t WS_IMG  = 1048576;   // 8 MB bf16: [chunk 256][f 256][j 64] (unswizzled)

__device__ __forceinline__ f32x4 MFMA(bf16x8 a, bf16x8 b, f32x4 c) {
  return __builtin_amdgcn_mfma_f32_16x16x32_bf16(a, b, c, 0, 0, 0);
}
__device__ __forceinline__ bf16x4 pack4(f32x4 v) {
  bf16x4 r; r[0]=(bf16)v[0]; r[1]=(bf16)v[1]; r[2]=(bf16)v[2]; r[3]=(bf16)v[3]; return r;
}
// 512B-row buffers: XOR bits 4-7 (16 slots)
__device__ __forceinline__ int swz512(int i, int inrow) { return i*512 + (inrow ^ ((i & 15) << 4)); }
// 128B-row buffers: XOR bits 4-6
__device__ __forceinline__ int swz128(int f, int inrow) { return f*128 + (inrow ^ ((f & 7) << 4)); }

// ---------------- prep: weights -> bf16 frag layout ; wa = W @ a (f32) -------
// frag[mat][kt(8)][nt(16)][lane(64)][jj(8)] ; element = W[kt*32+(l>>4)*8+jj][nt*16+(l&15)]
__global__ __launch_bounds__(256) void prep_weights(
    const float* __restrict__ W0, const float* __restrict__ W1,
    const float* __restrict__ W2, const float* __restrict__ W3,
    const float* __restrict__ a_vec,
    bf16* __restrict__ outw, float* __restrict__ wa)
{
  if (blockIdx.x == 128) {                 // wa[k] = dot(W0[k,:], a) (exact f32)
    int k = threadIdx.x;
    const float* row = W0 + k * Ff;
    float s = 0.f;
    for (int j = 0; j < Ff; j += 4) {
      f32x4 wv = *(const f32x4*)(row + j);
      f32x4 av = *(const f32x4*)(a_vec + j);
      s += wv[0]*av[0] + wv[1]*av[1] + wv[2]*av[2] + wv[3]*av[3];
    }
    wa[k] = s;
    return;
  }
  int t = blockIdx.x * 256 + threadIdx.x;  // [0, 32768)
  int l = t & 63, nt = (t >> 6) & 15, kt = (t >> 10) & 7, mat = t >> 13;
  const float* src = (mat==0) ? W0 : (mat==1) ? W1 : (mat==2) ? W2 : W3;
  int n  = nt*16 + (l & 15);
  int k0 = kt*32 + (l >> 4)*8;
  bf16x8 v;
  #pragma unroll
  for (int jj = 0; jj < 8; ++jj) v[jj] = (bf16)src[(k0 + jj)*Ff + n];
  *(bf16x8*)(outw + (size_t)t * 8) = v;
}

// ---------------- stage 1: Wh^T image + e. Plain row-tiled GEMM --------------
// 1024 blocks x 256 thr; block = 16 global rows. No LDS, no barriers.
__global__ __launch_bounds__(256, 4) void wh_e(
    const float* __restrict__ h, const bf16* __restrict__ wfrag,
    const float* __restrict__ wa, bf16* __restrict__ img, float* __restrict__ ews)
{
  const int t = threadIdx.x, l = t & 63, w = t >> 6, g = l >> 4, li = l & 15;
  const int rb = blockIdx.x * 16;          // global row base

  // e for rows rb..rb+15: 16 thr/row, 16 cols each (mirrors fused-kernel order)
  {
    const int r = t >> 4, s16 = t & 15;
    const float* hp = h + (size_t)(rb + r) * Ff + s16 * 16;
    float p = 0.f;
    #pragma unroll
    for (int u = 0; u < 2; ++u) {
      f32x4 h0 = *(const f32x4*)(hp + u*8);
      f32x4 h1 = *(const f32x4*)(hp + u*8 + 4);
      f32x4 w0 = *(const f32x4*)(wa + s16*16 + u*8);
      f32x4 w1 = *(const f32x4*)(wa + s16*16 + u*8 + 4);
      p += h0[0]*w0[0]+h0[1]*w0[1]+h0[2]*w0[2]+h0[3]*w0[3]
         + h1[0]*w1[0]+h1[1]*w1[1]+h1[2]*w1[2]+h1[3]*w1[3];
    }
    p += __shfl_xor(p, 1); p += __shfl_xor(p, 2);
    p += __shfl_xor(p, 4); p += __shfl_xor(p, 8);
    if (s16 == 0) ews[rb + r] = (p >= 0.f) ? p : ALPHA * p;
  }

  // GEMM: C[j=16 rows][f=256]; wave w owns f-tiles w*4+q. A direct from global.
  f32x4 acc[4];
  #pragma unroll
  for (int q = 0; q < 4; ++q) acc[q] = (f32x4){0.f,0.f,0.f,0.f};
  const float* ap0 = h + (size_t)(rb + li) * Ff + g*8;
  #pragma unroll
  for (int kt = 0; kt < 8; ++kt) {
    f32x4 a0 = *(const f32x4*)(ap0 + kt*32);
    f32x4 a1 = *(const f32x4*)(ap0 + kt*32 + 4);
    bf16x8 af;
    #pragma unroll
    for (int d = 0; d < 4; ++d) { af[d] = (bf16)a0[d]; af[4+d] = (bf16)a1[d]; }
    #pragma unroll
    for (int q = 0; q < 4; ++q) {
      bf16x8 bfr = *(const bf16x8*)(wfrag + (((size_t)kt*16 + (w*4 + q))*64 + l)*8);
      acc[q] = MFMA(af, bfr, acc[q]);
    }
  }
  // store WhT image: chunk = blockIdx>>2 ; j = (blockIdx&3)*16 + g*4 + e
  bf16* ib = img + (size_t)(blockIdx.x >> 2) * (Ff * Kk);
  const int j0 = (blockIdx.x & 3)*16 + g*4;
  #pragma unroll
  for (int q = 0; q < 4; ++q) {
    int f = (w*4 + q)*16 + li;           // C col = lane&15 -> f dim
    *(bf16x4*)(ib + f*64 + j0) = pack4(acc[q]);
  }
}

// ---------------- stage 2: softmax + PV + MLP + LN (R8 tail verbatim) --------
// 256 blocks x 1024 thr, 1 chunk/block.
__global__ __launch_bounds__(1024, 4) void gat2(
    const float* __restrict__ adj,
    const float* __restrict__ gln, const float* __restrict__ bln,
    const float* __restrict__ b1,  const float* __restrict__ b2,
    const float* __restrict__ b3,
    const bf16* __restrict__ wfrag, const bf16* __restrict__ img,
    const float* __restrict__ ews,  float* __restrict__ out)
{
  __shared__ __align__(16) bf16 bufA[Ff * Kk];   // whcT [256 f][64 j] (swz128) -> y1 (swz512)
  __shared__ __align__(16) bf16 bufB[Kk * Ff];   // x [64 i][256 f] -> y2 (swz512)
  __shared__ __align__(16) bf16 sS[Kk * Kk];     // S [64 i][64 j] (swz128)
  __shared__ float lnS[Kk * 8], lnQ[Kk * 8];

  const int t = threadIdx.x, l = t & 63, w = t >> 6, g = l >> 4, li = l & 15;
  const int wf = w & 7;            // f-group
  const int wi = w >> 3;           // i-group
  const int bc = blockIdx.x, b = bc >> 6, c = bc & 63;
  const size_t rbase = (size_t)b * Nn + c * Kk;

  // adj prefetch: wave w rows w*4+rr, lane = j
  float adjv[4];
  #pragma unroll
  for (int rr = 0; rr < 4; ++rr)
    adjv[rr] = adj[(rbase + w*4 + rr) * Nn + (size_t)c*Kk + l];

  // issue image loads (32 KB coalesced) — in flight across softmax
  const uint4* src = (const uint4*)(img + (size_t)bc * (Ff * Kk));
  uint4 im0 = src[t];
  uint4 im1 = src[t + 1024];

  // softmax rows w*4+rr -> S bf16 swizzled
  #pragma unroll
  for (int rr = 0; rr < 4; ++rr) {
    int i = w*4 + rr;
    float ev = ews[bc*64 + i];
    float x = adjv[rr] * ev;
    float m = x;
    #pragma unroll
    for (int off = 32; off; off >>= 1) m = fmaxf(m, __shfl_xor(m, off));
    float pe = __expf(x - m);
    float s = pe;
    #pragma unroll
    for (int off = 32; off; off >>= 1) s += __shfl_xor(s, off);
    *(bf16*)((char*)sS + swz128(i, l*2)) = (bf16)(pe / s);
  }

  // write image into bufA with the swz128 layout (16B chunks move atomically)
  {
    int off = t * 16;
    int f = off >> 7, ir = off & 127;
    *(uint4*)((char*)bufA + f*128 + (ir ^ ((f & 7) << 4))) = im0;
    off = (t + 1024) * 16;
    f = off >> 7; ir = off & 127;
    *(uint4*)((char*)bufA + f*128 + (ir ^ ((f & 7) << 4))) = im1;
  }
  __syncthreads();   // B1: whcT + sS ready

  // ---------------- PV: xT = whcT @ S^T -> x row-major ----------------
  f32x4 xr[2][2];    // [nt: i-tile][r: f-tile] — residual in regs
  #pragma unroll
  for (int nt = 0; nt < 2; ++nt)
    #pragma unroll
    for (int r = 0; r < 2; ++r) xr[nt][r] = (f32x4){0.f,0.f,0.f,0.f};
  #pragma unroll
  for (int kt = 0; kt < 2; ++kt) {
    int koff = (kt*32 + g*8)*2;
    bf16x8 af[2], bfr[2];
    #pragma unroll
    for (int r = 0; r < 2; ++r) {
      int f = (wf*2 + r)*16 + li;
      af[r] = *(const bf16x8*)((const char*)bufA + swz128(f, koff));
    }
    #pragma unroll
    for (int nt = 0; nt < 2; ++nt) {
      int i = (wi*2 + nt)*16 + li;
      bfr[nt] = *(const bf16x8*)((const char*)sS + swz128(i, koff));
    }
    #pragma unroll
    for (int nt = 0; nt < 2; ++nt)
      #pragma unroll
      for (int r = 0; r < 2; ++r)
        xr[nt][r] = MFMA(af[r], bfr[nt], xr[nt][r]);
  }
  #pragma unroll
  for (int nt = 0; nt < 2; ++nt) {
    int i = (wi*2 + nt)*16 + li;
    #pragma unroll
    for (int r = 0; r < 2; ++r) {
      int f0 = (wf*2 + r)*16 + g*4;
      *(bf16x4*)((char*)bufB + swz512(i, f0*2)) = pack4(xr[nt][r]);
    }
  }
  __syncthreads();   // B2: x complete (all bufA whcT reads done)

  // ---------------- MLP (transposed), 1 barrier per transition ----------------
  f32x4 acc3[2][2];
  #pragma unroll
  for (int stage = 0; stage < 3; ++stage) {
    const bf16* inB = (stage == 1) ? bufA : bufB;   // x -> y1 -> y2
    #pragma unroll
    for (int nt = 0; nt < 2; ++nt)
      #pragma unroll
      for (int r = 0; r < 2; ++r) acc3[nt][r] = (f32x4){0.f,0.f,0.f,0.f};
    #pragma unroll
    for (int kt = 0; kt < 8; ++kt) {
      bf16x8 af[2], bfr[2];
      #pragma unroll
      for (int r = 0; r < 2; ++r)
        af[r] = *(const bf16x8*)(wfrag + ((((size_t)(stage+1)*8 + kt)*16 + (wf*2 + r))*64 + l)*8);
      #pragma unroll
      for (int nt = 0; nt < 2; ++nt) {
        int i = (wi*2 + nt)*16 + li;
        bfr[nt] = *(const bf16x8*)((const char*)inB + swz512(i, (kt*32 + g*8)*2));
      }
      #pragma unroll
      for (int nt = 0; nt < 2; ++nt)
        #pragma unroll
        for (int r = 0; r < 2; ++r)
          acc3[nt][r] = MFMA(af[r], bfr[nt], acc3[nt][r]);
    }
    if (stage == 2) break;
    const float* bias = (stage == 0) ? b1 : b2;
    bf16* outB = (stage == 0) ? bufA : bufB;
    #pragma unroll
    for (int nt = 0; nt < 2; ++nt) {
      int i = (wi*2 + nt)*16 + li;
      #pragma unroll
      for (int r = 0; r < 2; ++r) {
        f32x4 v;
        #pragma unroll
        for (int e = 0; e < 4; ++e) {
          float x = acc3[nt][r][e] + bias[(wf*2 + r)*16 + g*4 + e];
          v[e] = (x >= 0.f) ? x : MLP_ALPHA * x;
        }
        int f0 = (wf*2 + r)*16 + g*4;
        *(bf16x4*)((char*)outB + swz512(i, f0*2)) = pack4(v);
      }
    }
    __syncthreads();   // B3 / B4
  }

  // ---------------- epilogue: +b3 +x ; LayerNorm over f ; store ----------------
  {
    float bv[2][4], gv[2][4], btv[2][4];
    #pragma unroll
    for (int r = 0; r < 2; ++r)
      #pragma unroll
      for (int e = 0; e < 4; ++e) {
        int f = (wf*2 + r)*16 + g*4 + e;
        bv[r][e] = b3[f]; gv[r][e] = gln[f]; btv[r][e] = bln[f];
      }
    #pragma unroll
    for (int nt = 0; nt < 2; ++nt) {
      float s = 0.f, qq = 0.f;
      #pragma unroll
      for (int r = 0; r < 2; ++r)
        #pragma unroll
        for (int e = 0; e < 4; ++e) {
          float z = acc3[nt][r][e] + bv[r][e] + xr[nt][r][e];
          acc3[nt][r][e] = z;
          s += z; qq += z*z;
        }
      s  += __shfl_xor(s, 16);  s  += __shfl_xor(s, 32);   // reduce over g
      qq += __shfl_xor(qq, 16); qq += __shfl_xor(qq, 32);
      if (g == 0) {
        int i = (wi*2 + nt)*16 + li;
        lnS[i*8 + wf] = s;
        lnQ[i*8 + wf] = qq;
      }
    }
    __syncthreads();   // B5: LN partials
    #pragma unroll
    for (int nt = 0; nt < 2; ++nt) {
      int i = (wi*2 + nt)*16 + li;
      f32x4 s0 = *(const f32x4*)&lnS[i*8];
      f32x4 s1 = *(const f32x4*)&lnS[i*8 + 4];
      f32x4 q0 = *(const f32x4*)&lnQ[i*8];
      f32x4 q1 = *(const f32x4*)&lnQ[i*8 + 4];
      float s  = s0[0]+s0[1]+s0[2]+s0[3]+s1[0]+s1[1]+s1[2]+s1[3];
      float qq = q0[0]+q0[1]+q0[2]+q0[3]+q1[0]+q1[1]+q1[2]+q1[3];
      float mu  = s * (1.f/256.f);
      float var = qq * (1.f/256.f) - mu*mu;
      float rs  = rsqrtf(var + LN_EPS);
      #pragma unroll
      for (int r = 0; r < 2; ++r) {
        float4 o;
        o.x = (acc3[nt][r][0] - mu)*rs*gv[r][0] + btv[r][0];
        o.y = (acc3[nt][r][1] - mu)*rs*gv[r][1] + btv[r][1];
        o.z = (acc3[nt][r][2] - mu)*rs*gv[r][2] + btv[r][2];
        o.w = (acc3[nt][r][3] - mu)*rs*gv[r][3] + btv[r][3];
        *(float4*)&out[(rbase + i)*Ff + (wf*2 + r)*16 + g*4] = o;
      }
    }
  }
}

extern "C" void kernel_launch(void* const* d_in, const int* in_sizes, int n_in,
                              void* d_out, int out_size, void* d_ws, size_t ws_size,
                              hipStream_t stream) {
  (void)in_sizes; (void)n_in; (void)out_size; (void)ws_size;
  bf16*  wfrag = (bf16*)d_ws;
  float* wa    = (float*)((char*)d_ws + WS_WA);
  float* ews   = (float*)((char*)d_ws + WS_EVEC);
  bf16*  img   = (bf16*)((char*)d_ws + WS_IMG);
  prep_weights<<<dim3(129), dim3(256), 0, stream>>>(
      (const float*)d_in[2], (const float*)d_in[6],
      (const float*)d_in[8], (const float*)d_in[10],
      (const float*)d_in[3], wfrag, wa);
  wh_e<<<dim3(1024), dim3(256), 0, stream>>>(
      (const float*)d_in[0], wfrag, wa, img, ews);
  gat2<<<dim3(Bb * Cc), dim3(1024), 0, stream>>>(
      (const float*)d_in[1],
      (const float*)d_in[4],  (const float*)d_in[5],
      (const float*)d_in[7],  (const float*)d_in[9],  (const float*)d_in[11],
      wfrag, img, ews, (float*)d_out);
}

// Round 12
// 37.257 us; speedup vs baseline: 1.3203x; 1.3203x over previous
//
#include <hip/hip_runtime.h>

typedef __bf16 bf16;
typedef __bf16 bf16x4 __attribute__((ext_vector_type(4)));
typedef __bf16 bf16x8 __attribute__((ext_vector_type(8)));
typedef float  f32x4  __attribute__((ext_vector_type(4)));

#define ALPHA 0.2f
#define MLP_ALPHA 0.01f
#define LN_EPS 1e-5f

constexpr int Bb = 4;
constexpr int Nn = 4096;
constexpr int Ff = 256;   // FIN == FOUT
constexpr int Kk = 64;    // chunk rows
constexpr int Cc = 64;    // N / k

__device__ __forceinline__ f32x4 MFMA(bf16x8 a, bf16x8 b, f32x4 c) {
  return __builtin_amdgcn_mfma_f32_16x16x32_bf16(a, b, c, 0, 0, 0);
}
__device__ __forceinline__ bf16x4 pack4(f32x4 v) {
  bf16x4 r; r[0]=(bf16)v[0]; r[1]=(bf16)v[1]; r[2]=(bf16)v[2]; r[3]=(bf16)v[3]; return r;
}
// 512B-row buffers: XOR bits 4-7 (16 slots)
__device__ __forceinline__ int swz512(int i, int inrow) { return i*512 + (inrow ^ ((i & 15) << 4)); }
// 128B-row buffers: XOR bits 4-6
__device__ __forceinline__ int swz128(int f, int inrow) { return f*128 + (inrow ^ ((f & 7) << 4)); }

// ---------------- prep: weights -> bf16 frag layout ; wa = W @ a (f32) -------
// frag[mat][kt(8)][nt(16)][lane(64)][jj(8)] ; element = W[kt*32+(l>>4)*8+jj][nt*16+(l&15)]
__global__ __launch_bounds__(256) void prep_weights(
    const float* __restrict__ W0, const float* __restrict__ W1,
    const float* __restrict__ W2, const float* __restrict__ W3,
    const float* __restrict__ a_vec,
    bf16* __restrict__ outw, float* __restrict__ wa)
{
  if (blockIdx.x == 128) {                 // wa[k] = dot(W0[k,:], a) (exact f32)
    int k = threadIdx.x;
    const float* row = W0 + k * Ff;
    float s = 0.f;
    for (int j = 0; j < Ff; j += 4) {
      f32x4 wv = *(const f32x4*)(row + j);
      f32x4 av = *(const f32x4*)(a_vec + j);
      s += wv[0]*av[0] + wv[1]*av[1] + wv[2]*av[2] + wv[3]*av[3];
    }
    wa[k] = s;
    return;
  }
  int t = blockIdx.x * 256 + threadIdx.x;  // [0, 32768)
  int l = t & 63, nt = (t >> 6) & 15, kt = (t >> 10) & 7, mat = t >> 13;
  const float* src = (mat==0) ? W0 : (mat==1) ? W1 : (mat==2) ? W2 : W3;
  int n  = nt*16 + (l & 15);
  int k0 = kt*32 + (l >> 4)*8;
  bf16x8 v;
  #pragma unroll
  for (int jj = 0; jj < 8; ++jj) v[jj] = (bf16)src[(k0 + jj)*Ff + n];
  *(bf16x8*)(outw + (size_t)t * 8) = v;
}

__device__ __forceinline__ void prefetch_af(const bf16* __restrict__ wfrag, int mat,
                                            bf16x8 pf[4][2], int w, int l) {
  #pragma unroll
  for (int kt = 0; kt < 4; ++kt)
    #pragma unroll
    for (int r = 0; r < 2; ++r)
      pf[kt][r] = *(const bf16x8*)(wfrag + ((((size_t)mat*8 + kt)*16 + (w*2 + r))*64 + l)*8);
}

// MLP stage: kt 0-3 weights come from pre-barrier prefetch regs, kt 4-7 inline.
__device__ __forceinline__ void mlp_stage(const bf16* __restrict__ wfrag, int mat,
                                          const bf16* inB, f32x4 acc[4][2],
                                          bf16x8 pf[4][2], int w, int l)
{
  const int g = l >> 4, li = l & 15;
  #pragma unroll
  for (int kt = 0; kt < 8; ++kt) {
    bf16x8 af[2];
    if (kt < 4) { af[0] = pf[kt][0]; af[1] = pf[kt][1]; }
    else {
      #pragma unroll
      for (int r = 0; r < 2; ++r)
        af[r] = *(const bf16x8*)(wfrag + ((((size_t)mat*8 + kt)*16 + (w*2 + r))*64 + l)*8);
    }
    bf16x8 bfr[4];
    #pragma unroll
    for (int nt = 0; nt < 4; ++nt) {
      int i = nt*16 + li;
      bfr[nt] = *(const bf16x8*)((const char*)inB + swz512(i, (kt*32 + g*8)*2));
    }
    #pragma unroll
    for (int nt = 0; nt < 4; ++nt)
      #pragma unroll
      for (int r = 0; r < 2; ++r)
        acc[nt][r] = MFMA(af[r], bfr[nt], acc[nt][r]);
  }
}

// One block per chunk, 8 waves, 5 barriers. whcT is wave-private => phase0->PV
// has NO barrier (same-wave LDS RAW is HW-ordered). Softmax runs pre-B1.
__global__ __launch_bounds__(512, 2) void gat_mfma(
    const float* __restrict__ h,   const float* __restrict__ adj,
    const float* __restrict__ gln, const float* __restrict__ bln,
    const float* __restrict__ b1,  const float* __restrict__ b2,
    const float* __restrict__ b3,
    const bf16* __restrict__ wfrag, const float* __restrict__ wa,
    float* __restrict__ out)
{
  __shared__ bf16 hbs[Kk * Ff];    // h chunk bf16, swz512 rows
  __shared__ bf16 bufA[Ff * Kk];   // whcT [256 f][64 j] (swz128, wave-private panels) -> y1 (swz512)
  __shared__ bf16 bufB[Kk * Ff];   // x [64 i][256 f] -> y2 (swz512)
  __shared__ bf16 sS[Kk * Kk];     // S [64 i][64 j] (swz128)
  __shared__ float lnS[Kk * 8], lnQ[Kk * 8];

  const int t = threadIdx.x, l = t & 63, w = t >> 6, g = l >> 4, li = l & 15;
  const int bc = blockIdx.x, b = bc >> 6, c = bc & 63;
  const size_t rbase = (size_t)b * Nn + c * Kk;

  // adj prefetch: wave w rows w*8+rr, lane = j
  float adjv[8];
  #pragma unroll
  for (int rr = 0; rr < 8; ++rr)
    adjv[rr] = adj[(rbase + w*8 + rr) * Nn + (size_t)c*Kk + l];

  // ---------------- stage h -> LDS bf16 ; e in registers ----------------
  // lane covers row w*8+(l>>3), cols (l&7)*32 .. +31  (same math/order as R3)
  float pl;
  {
    const int i  = t >> 3;
    const int k0 = (t & 7) * 32;
    const float* hp = h + (rbase + i) * Ff + k0;
    float p = 0.f;
    #pragma unroll
    for (int u = 0; u < 4; ++u) {
      f32x4 h0 = *(const f32x4*)(hp + u*8);
      f32x4 h1 = *(const f32x4*)(hp + u*8 + 4);
      f32x4 w0 = *(const f32x4*)(wa + k0 + u*8);
      f32x4 w1 = *(const f32x4*)(wa + k0 + u*8 + 4);
      p += h0[0]*w0[0] + h0[1]*w0[1] + h0[2]*w0[2] + h0[3]*w0[3]
         + h1[0]*w1[0] + h1[1]*w1[1] + h1[2]*w1[2] + h1[3]*w1[3];
      bf16x8 v;
      #pragma unroll
      for (int d = 0; d < 4; ++d) { v[d] = (bf16)h0[d]; v[4+d] = (bf16)h1[d]; }
      *(bf16x8*)((char*)hbs + swz512(i, (k0 + u*8)*2)) = v;
    }
    p += __shfl_xor(p, 1); p += __shfl_xor(p, 2); p += __shfl_xor(p, 4);
    pl = (p >= 0.f) ? p : ALPHA * p;   // e for row w*8+(l>>3), held by all 8 lanes of the group
  }

  // ---------------- softmax (rows w*8+rr, own-wave e) -> S pre-B1 -------------
  #pragma unroll
  for (int rr = 0; rr < 8; ++rr) {
    int i = w*8 + rr;
    float e  = __shfl(pl, rr*8);
    float x  = adjv[rr] * e;
    float m = x;
    #pragma unroll
    for (int off = 32; off; off >>= 1) m = fmaxf(m, __shfl_xor(m, off));
    float pe = __expf(x - m);
    float s = pe;
    #pragma unroll
    for (int off = 32; off; off >>= 1) s += __shfl_xor(s, off);
    *(bf16*)((char*)sS + swz128(i, l*2)) = (bf16)(pe / s);
  }
  __syncthreads();   // B1: hbs + sS complete (cheap drain: all waves arrive together)

  // ---------------- phase 0: whcT = (h @ W)^T  (A from LDS) ----------------
  f32x4 acc1[2][4];   // [q: f col-tile][rt: j row-tile]
  #pragma unroll
  for (int q = 0; q < 2; ++q)
    #pragma unroll
    for (int rt = 0; rt < 4; ++rt) acc1[q][rt] = (f32x4){0.f,0.f,0.f,0.f};
  #pragma unroll
  for (int kt = 0; kt < 8; ++kt) {
    bf16x8 af[4];
    #pragma unroll
    for (int rt = 0; rt < 4; ++rt) {
      int i = rt*16 + li;
      af[rt] = *(const bf16x8*)((const char*)hbs + swz512(i, (kt*32 + g*8)*2));
    }
    #pragma unroll
    for (int q = 0; q < 2; ++q) {
      bf16x8 bfr = *(const bf16x8*)(wfrag + (((size_t)kt*16 + (w*2 + q))*64 + l)*8);
      #pragma unroll
      for (int rt = 0; rt < 4; ++rt) acc1[q][rt] = MFMA(af[rt], bfr, acc1[q][rt]);
    }
  }
  // whcT store — wave-private panel; NO barrier before PV (same-wave LDS order)
  #pragma unroll
  for (int q = 0; q < 2; ++q) {
    int f = (w*2 + q)*16 + li;
    #pragma unroll
    for (int rt = 0; rt < 4; ++rt) {
      int j0 = rt*16 + g*4;
      *(bf16x4*)((char*)bufA + swz128(f, j0*2)) = pack4(acc1[q][rt]);
    }
  }

  // ---------------- PV: xT = whcT @ S^T -> x row-major ----------------
  f32x4 xr[4][2];    // residual, kept in regs
  #pragma unroll
  for (int nt = 0; nt < 4; ++nt)
    #pragma unroll
    for (int r = 0; r < 2; ++r) xr[nt][r] = (f32x4){0.f,0.f,0.f,0.f};
  #pragma unroll
  for (int kt = 0; kt < 2; ++kt) {
    int koff = (kt*32 + g*8)*2;
    bf16x8 af[2], bfr[4];
    #pragma unroll
    for (int r = 0; r < 2; ++r) {
      int f = (w*2 + r)*16 + li;
      af[r] = *(const bf16x8*)((const char*)bufA + swz128(f, koff));   // own panel
    }
    #pragma unroll
    for (int nt = 0; nt < 4; ++nt) {
      int i = nt*16 + li;
      bfr[nt] = *(const bf16x8*)((const char*)sS + swz128(i, koff));   // ordered by B1
    }
    #pragma unroll
    for (int nt = 0; nt < 4; ++nt)
      #pragma unroll
      for (int r = 0; r < 2; ++r)
        xr[nt][r] = MFMA(af[r], bfr[nt], xr[nt][r]);
  }
  #pragma unroll
  for (int nt = 0; nt < 4; ++nt) {
    int i = nt*16 + li;
    #pragma unroll
    for (int r = 0; r < 2; ++r) {
      int f0 = (w*2 + r)*16 + g*4;
      *(bf16x4*)((char*)bufB + swz512(i, f0*2)) = pack4(xr[nt][r]);
    }
  }

  // ---------------- MLP: 3 stages, weight prefetch across each barrier --------
  bf16x8 pf[4][2];
  f32x4 acc3[4][2];
  prefetch_af(wfrag, 1, pf, w, l);     // issued pre-barrier; drained at barrier
  __syncthreads();   // B2: x ready; whcT reads (pre-barrier, own-wave) done

  #pragma unroll
  for (int nt = 0; nt < 4; ++nt)
    #pragma unroll
    for (int r = 0; r < 2; ++r) acc3[nt][r] = (f32x4){0.f,0.f,0.f,0.f};
  mlp_stage(wfrag, 1, bufB, acc3, pf, w, l);       // y1 = leaky(x W1 + b1)
  #pragma unroll
  for (int nt = 0; nt < 4; ++nt) {
    int i = nt*16 + li;
    #pragma unroll
    for (int r = 0; r < 2; ++r) {
      f32x4 v;
      #pragma unroll
      for (int e = 0; e < 4; ++e) {
        float x = acc3[nt][r][e] + b1[(w*2 + r)*16 + g*4 + e];
        v[e] = (x >= 0.f) ? x : MLP_ALPHA * x;
      }
      int f0 = (w*2 + r)*16 + g*4;
      *(bf16x4*)((char*)bufA + swz512(i, f0*2)) = pack4(v);
    }
  }
  prefetch_af(wfrag, 2, pf, w, l);
  __syncthreads();   // B3: y1 ready; bufB x-reads done

  #pragma unroll
  for (int nt = 0; nt < 4; ++nt)
    #pragma unroll
    for (int r = 0; r < 2; ++r) acc3[nt][r] = (f32x4){0.f,0.f,0.f,0.f};
  mlp_stage(wfrag, 2, bufA, acc3, pf, w, l);       // y2 = leaky(y1 W2 + b2)
  #pragma unroll
  for (int nt = 0; nt < 4; ++nt) {
    int i = nt*16 + li;
    #pragma unroll
    for (int r = 0; r < 2; ++r) {
      f32x4 v;
      #pragma unroll
      for (int e = 0; e < 4; ++e) {
        float x = acc3[nt][r][e] + b2[(w*2 + r)*16 + g*4 + e];
        v[e] = (x >= 0.f) ? x : MLP_ALPHA * x;
      }
      int f0 = (w*2 + r)*16 + g*4;
      *(bf16x4*)((char*)bufB + swz512(i, f0*2)) = pack4(v);
    }
  }
  prefetch_af(wfrag, 3, pf, w, l);
  __syncthreads();   // B4: y2 ready; bufA y1-reads done

  #pragma unroll
  for (int nt = 0; nt < 4; ++nt)
    #pragma unroll
    for (int r = 0; r < 2; ++r) acc3[nt][r] = (f32x4){0.f,0.f,0.f,0.f};
  mlp_stage(wfrag, 3, bufB, acc3, pf, w, l);       // y3 = y2 W3 (+b3 in epilogue)

  // ---------------- epilogue: +b3 +x ; LayerNorm over f ; store ----------------
  {
    float bv[2][4], gv[2][4], btv[2][4];
    #pragma unroll
    for (int r = 0; r < 2; ++r)
      #pragma unroll
      for (int e = 0; e < 4; ++e) {
        int f = (w*2 + r)*16 + g*4 + e;
        bv[r][e] = b3[f]; gv[r][e] = gln[f]; btv[r][e] = bln[f];
      }
    #pragma unroll
    for (int nt = 0; nt < 4; ++nt) {
      float s = 0.f, qq = 0.f;
      #pragma unroll
      for (int r = 0; r < 2; ++r)
        #pragma unroll
        for (int e = 0; e < 4; ++e) {
          float z = acc3[nt][r][e] + bv[r][e] + xr[nt][r][e];
          acc3[nt][r][e] = z;
          s += z; qq += z*z;
        }
      s  += __shfl_xor(s, 16);  s  += __shfl_xor(s, 32);
      qq += __shfl_xor(qq, 16); qq += __shfl_xor(qq, 32);
      if (g == 0) {
        int i = nt*16 + li;
        lnS[i*8 + w] = s;
        lnQ[i*8 + w] = qq;
      }
    }
    __syncthreads();   // B5: LN partials
    #pragma unroll
    for (int nt = 0; nt < 4; ++nt) {
      int i = nt*16 + li;
      f32x4 s0 = *(const f32x4*)&lnS[i*8];
      f32x4 s1 = *(const f32x4*)&lnS[i*8 + 4];
      f32x4 q0 = *(const f32x4*)&lnQ[i*8];
      f32x4 q1 = *(const f32x4*)&lnQ[i*8 + 4];
      float s  = s0[0]+s0[1]+s0[2]+s0[3]+s1[0]+s1[1]+s1[2]+s1[3];
      float qq = q0[0]+q0[1]+q0[2]+q0[3]+q1[0]+q1[1]+q1[2]+q1[3];
      float mu  = s * (1.f/256.f);
      float var = qq * (1.f/256.f) - mu*mu;
      float rs  = rsqrtf(var + LN_EPS);
      #pragma unroll
      for (int r = 0; r < 2; ++r) {
        float4 o;
        o.x = (acc3[nt][r][0] - mu)*rs*gv[r][0] + btv[r][0];
        o.y = (acc3[nt][r][1] - mu)*rs*gv[r][1] + btv[r][1];
        o.z = (acc3[nt][r][2] - mu)*rs*gv[r][2] + btv[r][2];
        o.w = (acc3[nt][r][3] - mu)*rs*gv[r][3] + btv[r][3];
        *(float4*)&out[(rbase + i)*Ff + (w*2 + r)*16 + g*4] = o;
      }
    }
  }
}

extern "C" void kernel_launch(void* const* d_in, const int* in_sizes, int n_in,
                              void* d_out, int out_size, void* d_ws, size_t ws_size,
                              hipStream_t stream) {
  (void)in_sizes; (void)n_in; (void)out_size; (void)ws_size;
  bf16*  wfrag = (bf16*)d_ws;                       // 512 KB
  float* wa    = (float*)((char*)d_ws + 512*1024);  // 1 KB
  prep_weights<<<dim3(129), dim3(256), 0, stream>>>(
      (const float*)d_in[2], (const float*)d_in[6],
      (const float*)d_in[8], (const float*)d_in[10],
      (const float*)d_in[3], wfrag, wa);
  gat_mfma<<<dim3(Bb * Cc), dim3(512), 0, stream>>>(
      (const float*)d_in[0],  (const float*)d_in[1],
      (const float*)d_in[4],  (const float*)d_in[5],
      (const float*)d_in[7],  (const float*)d_in[9],  (const float*)d_in[11],
      wfrag, wa, (float*)d_out);
}